// Round 7
// baseline (231.919 us; speedup 1.0000x reference)
//
#include <hip/hip_runtime.h>

// Blur = separable 4-tap FIR, taps [0.25,0.75,0.75,0.25], zero-pad (2,1)/(2,1).
// LDS-DMA pipeline: per-wave-private 8-row LDS ring filled by global_load_lds
// (no VGPR dest), hand-counted s_waitcnt vmcnt(N) (never drains the 5 in-flight
// stores), halo read straight from LDS (no bpermutes). h-window A/B/C in regs.

constexpr int W = 256;
constexpr int H = 256;
constexpr float F0 = 0.25f;
constexpr float F1 = 0.75f;

typedef float f32x4 __attribute__((ext_vector_type(4)));

__global__ __launch_bounds__(256) void blur_kernel(const float* __restrict__ x,
                                                   float* __restrict__ out) {
    // 4 waves x 8 ring slots x 1KB row = 32KB -> 5 blocks/CU (20 waves/CU).
    __shared__ float lds[4][8][W];
    const int plane = blockIdx.x;
    const int wave  = threadIdx.x >> 6;
    const int lane  = threadIdx.x & 63;
    const float* xp = x + (size_t)plane * (H * W);
    float*       op = out + (size_t)plane * (H * W);
    const int r0  = wave * 64;
    const int col = lane * 4;
    float* lbase = &lds[wave][0][0];   // private to this wave: no barriers

    // DMA one input row (clamped) into ring slot: LDS dest = base + lane*16.
    auto issue = [&](int row, int slot) {
        const int rc = row < 0 ? 0 : (row > H - 1 ? H - 1 : row);
        const float* g = xp + rc * W + col;
        __builtin_amdgcn_global_load_lds(
            (const __attribute__((address_space(1))) unsigned int*)g,
            (__attribute__((address_space(3))) unsigned int*)(lbase + slot * W),
            16, 0, 0);
    };

    // Horizontal 4-tap from an LDS row; halo via direct LDS reads (clamped
    // addresses at lanes 0/63, zeroed by select — the zero-pad).
    auto hrow = [&](int slot) -> float4 {
        const float* rowp = lbase + slot * W;
        float4 v = *reinterpret_cast<const float4*>(rowp + col);
        float2 L = *reinterpret_cast<const float2*>(rowp + (lane ? col - 2 : 0));
        float  R = rowp[lane < 63 ? col + 4 : 0];
        if (lane == 0)  { L.x = 0.f; L.y = 0.f; }
        if (lane == 63) { R = 0.f; }
        float4 h;
        h.x = F0 * L.x + F1 * L.y + F1 * v.x + F0 * v.y;
        h.y = F0 * L.y + F1 * v.x + F1 * v.y + F0 * v.z;
        h.z = F0 * v.x + F1 * v.y + F1 * v.z + F0 * v.w;
        h.w = F0 * v.y + F1 * v.z + F1 * v.w + F0 * R;
        return h;
    };

    // Prologue: rows r0-2 .. r0+5 into slots 0..7 (row r -> slot (r-r0+2)&7).
    #pragma unroll
    for (int k = 0; k < 8; ++k) issue(r0 - 2 + k, k);

    // Prime h-window: need slots 0..2 (rows r0-2..r0) -> oldest 3 loads done.
    asm volatile("s_waitcnt vmcnt(5)" ::: "memory");
    __builtin_amdgcn_sched_barrier(0);
    float4 A = hrow(0);
    float4 B = hrow(1);
    float4 C = hrow(2);
    if (r0 == 0) {  // rows -2,-1 are zero-pad (clamped loads held garbage)
        A.x = A.y = A.z = A.w = 0.f;
        B.x = B.y = B.z = B.w = 0.f;
    }

    // Per iteration t (output row io=r0+t): wait for load(row io+1) ->
    // ds_read+hfilt it -> vfilt -> issue load(row io+6, slot t&7) -> store io.
    // Counted waits: t=0..4 drain prologue loads (4,5,6,7,8); steady state has
    // 5 loads + 5 stores in flight -> vmcnt(9) retires exactly {oldest store,
    // next load} and never blocks on newer stores.
#define BLUR_ITER(T, WAITSTR)                                              \
    {                                                                      \
        const int io = r0 + (T);                                           \
        asm volatile(WAITSTR ::: "memory");                                \
        __builtin_amdgcn_sched_barrier(0);                                 \
        float4 D = hrow(((T) + 3) & 7);                                    \
        if (io + 1 >= H) { D.x = D.y = D.z = D.w = 0.f; }                  \
        f32x4 o;                                                           \
        o.x = F0 * (A.x + D.x) + F1 * (B.x + C.x);                         \
        o.y = F0 * (A.y + D.y) + F1 * (B.y + C.y);                         \
        o.z = F0 * (A.z + D.z) + F1 * (B.z + C.z);                         \
        o.w = F0 * (A.w + D.w) + F1 * (B.w + C.w);                         \
        issue(io + 6, (T) & 7);                                            \
        *reinterpret_cast<f32x4*>(op + io * W + col) = o;                  \
        A = B; B = C; C = D;                                               \
    }

    BLUR_ITER(0, "s_waitcnt vmcnt(4)");
    BLUR_ITER(1, "s_waitcnt vmcnt(5)");
    BLUR_ITER(2, "s_waitcnt vmcnt(6)");
    BLUR_ITER(3, "s_waitcnt vmcnt(7)");
    BLUR_ITER(4, "s_waitcnt vmcnt(8)");
    #pragma unroll 4
    for (int t = 5; t < 64; ++t) {
        BLUR_ITER(t, "s_waitcnt vmcnt(9)");
    }
#undef BLUR_ITER
}

extern "C" void kernel_launch(void* const* d_in, const int* in_sizes, int n_in,
                              void* d_out, int out_size, void* d_ws, size_t ws_size,
                              hipStream_t stream) {
    const float* x = (const float*)d_in[0];
    float* o = (float*)d_out;
    const int planes = in_sizes[0] / (H * W);  // N*C = 2048
    blur_kernel<<<planes, 256, 0, stream>>>(x, o);
}

// Round 8
// 208.421 us; speedup vs baseline: 1.1127x; 1.1127x over previous
//
#include <hip/hip_runtime.h>

// Blur = separable 4-tap FIR, taps [0.25,0.75,0.75,0.25], zero-pad (2,1)/(2,1).
// R6 deferred-store pipeline (consume -> refill loads -> stores, so waited-on
// loads stay older than in-flight stores) + full non-temporal streaming:
// NT loads (input streams once, > L3) and NT stores (output never re-read) to
// avoid allocate+evict churn on 1 GB of touch-once traffic.

constexpr int W = 256;
constexpr int H = 256;
constexpr float F0 = 0.25f;
constexpr float F1 = 0.75f;

typedef float f32x4 __attribute__((ext_vector_type(4)));

// Horizontal 4-tap pass. Lane l holds cols [4l,4l+3]; halo via 3 shuffles.
__device__ __forceinline__ f32x4 hfilt(const f32x4 v, const int lane) {
    float xl2 = __shfl_up(v.z, 1);
    float xl1 = __shfl_up(v.w, 1);
    float xr  = __shfl_down(v.x, 1);
    if (lane == 0)  { xl2 = 0.0f; xl1 = 0.0f; }
    if (lane == 63) { xr = 0.0f; }
    f32x4 h;
    h.x = F0 * xl2 + F1 * xl1 + F1 * v.x + F0 * v.y;
    h.y = F0 * xl1 + F1 * v.x + F1 * v.y + F0 * v.z;
    h.z = F0 * v.x + F1 * v.y + F1 * v.z + F0 * v.w;
    h.w = F0 * v.y + F1 * v.z + F1 * v.w + F0 * xr;
    return h;
}

// Vertical 4-tap: out = F0*(A+D) + F1*(B+C), componentwise.
__device__ __forceinline__ f32x4 vfilt(const f32x4 A, const f32x4 B,
                                       const f32x4 C, const f32x4 D) {
    f32x4 o;
    o.x = F0 * (A.x + D.x) + F1 * (B.x + C.x);
    o.y = F0 * (A.y + D.y) + F1 * (B.y + C.y);
    o.z = F0 * (A.z + D.z) + F1 * (B.z + C.z);
    o.w = F0 * (A.w + D.w) + F1 * (B.w + C.w);
    return o;
}

__global__ __launch_bounds__(256) void blur_kernel(const float* __restrict__ x,
                                                   float* __restrict__ out) {
    const int plane = blockIdx.x;
    const int wave  = threadIdx.x >> 6;
    const int lane  = threadIdx.x & 63;
    const float* xp = x + (size_t)plane * (H * W);
    float*       op = out + (size_t)plane * (H * W);
    const int r0  = wave * 64;
    const int col = lane * 4;

    auto loadrow = [&](int i) -> f32x4 {
        if ((unsigned)i >= (unsigned)H) return f32x4{0.f, 0.f, 0.f, 0.f};
        return __builtin_nontemporal_load(
            reinterpret_cast<const f32x4*>(xp + i * W + col));
    };
    auto storerow = [&](int i, const f32x4 o) {
        __builtin_nontemporal_store(o, reinterpret_cast<f32x4*>(op + i * W + col));
    };

    // Rolling window of hfilt'd rows: out io needs h(io-2),h(io-1),h(io),h(io+1).
    f32x4 A = hfilt(loadrow(r0 - 2), lane);
    f32x4 B = hfilt(loadrow(r0 - 1), lane);
    f32x4 C = hfilt(loadrow(r0), lane);

    // Two 4-row raw-input buffers, 8 rows in flight (named: static indexing).
    f32x4 a0 = loadrow(r0 + 1), a1 = loadrow(r0 + 2),
          a2 = loadrow(r0 + 3), a3 = loadrow(r0 + 4);
    f32x4 b0 = loadrow(r0 + 5), b1 = loadrow(r0 + 6),
          b2 = loadrow(r0 + 7), b3 = loadrow(r0 + 8);

#pragma unroll
    for (int g = 0; g < 8; ++g) {
        const int base = r0 + 8 * g;   // outputs base..base+7 this group

        // ---- half 1: consume a (rows base+1..base+4), outputs base..base+3
        f32x4 D0 = hfilt(a0, lane), D1 = hfilt(a1, lane),
              D2 = hfilt(a2, lane), D3 = hfilt(a3, lane);
        f32x4 o0 = vfilt(A,  B,  C,  D0);
        f32x4 o1 = vfilt(B,  C,  D0, D1);
        f32x4 o2 = vfilt(C,  D0, D1, D2);
        f32x4 o3 = vfilt(D0, D1, D2, D3);
        A = D1; B = D2; C = D3;
        if (g < 7) {  // refill a with rows base+9..base+12 BEFORE the stores
            a0 = loadrow(base + 9);  a1 = loadrow(base + 10);
            a2 = loadrow(base + 11); a3 = loadrow(base + 12);
        }
        storerow(base,     o0); storerow(base + 1, o1);
        storerow(base + 2, o2); storerow(base + 3, o3);

        // ---- half 2: consume b (rows base+5..base+8), outputs base+4..base+7
        f32x4 E0 = hfilt(b0, lane), E1 = hfilt(b1, lane),
              E2 = hfilt(b2, lane), E3 = hfilt(b3, lane);
        f32x4 p0 = vfilt(A,  B,  C,  E0);
        f32x4 p1 = vfilt(B,  C,  E0, E1);
        f32x4 p2 = vfilt(C,  E0, E1, E2);
        f32x4 p3 = vfilt(E0, E1, E2, E3);
        A = E1; B = E2; C = E3;
        if (g < 7) {  // refill b with rows base+13..base+16 BEFORE the stores
            b0 = loadrow(base + 13); b1 = loadrow(base + 14);
            b2 = loadrow(base + 15); b3 = loadrow(base + 16);
        }
        storerow(base + 4, p0); storerow(base + 5, p1);
        storerow(base + 6, p2); storerow(base + 7, p3);
    }
}

extern "C" void kernel_launch(void* const* d_in, const int* in_sizes, int n_in,
                              void* d_out, int out_size, void* d_ws, size_t ws_size,
                              hipStream_t stream) {
    const float* x = (const float*)d_in[0];
    float* o = (float*)d_out;
    const int planes = in_sizes[0] / (H * W);  // N*C = 2048
    blur_kernel<<<planes, 256, 0, stream>>>(x, o);
}